// Round 9
// baseline (147.890 us; speedup 1.0000x reference)
//
#include <hip/hip_runtime.h>
#include <hip/hip_bf16.h>

#define N_NODES 2048
#define EMB 768
#define NH 8
#define DH 96
#define ALPHA 0.2f
#define SCALE 0.10206207261596575f  // 96^-0.5
#define NGMAX 192
#define WSZ (EMB * EMB)

typedef __bf16 bf16x8 __attribute__((ext_vector_type(8)));
typedef float f32x4 __attribute__((ext_vector_type(4)));
typedef __attribute__((address_space(3))) unsigned int lds_u32;
typedef __attribute__((address_space(1))) const unsigned int glb_u32;

union pack4 { ushort4 u; __hip_bfloat16 h[4]; };

// ---------------------------------------------------------------- prep: concat-cast e + cast 3 weights + zero cnt/s1/s2
__global__ __launch_bounds__(256) void prep_kernel(
    const float* __restrict__ eh, const float* __restrict__ er, const float* __restrict__ et,
    const float* __restrict__ W0, const float* __restrict__ W1, const float* __restrict__ W2,
    __hip_bfloat16* __restrict__ e, __hip_bfloat16* __restrict__ o0,
    __hip_bfloat16* __restrict__ o1, __hip_bfloat16* __restrict__ o2,
    int* __restrict__ cnt, float* __restrict__ s12z)
{
    const int b = blockIdx.x;
    const int t = threadIdx.x;
    if (b >= 3264) {                      // 32 blocks: zero s1+s2 (32768 floats) + cnt
        int zi = (b - 3264) * 256 + t;    // 0..8191
        float4 z = {0.f, 0.f, 0.f, 0.f};
        *reinterpret_cast<float4*>(s12z + (size_t)zi * 4) = z;
        if (zi < 32) cnt[zi] = 0;
        return;
    }
    const int gtid = b * 256 + t;
    const float* src;
    __hip_bfloat16* dst;
    if (b < 1536) {                       // e = concat(eh,er,et)
        int idx = gtid * 4;
        int i = idx / EMB, c = idx % EMB;
        if (c < 256)      src = eh + i * 256 + c;
        else if (c < 512) src = er + i * 256 + (c - 256);
        else              src = et + i * 256 + (c - 512);
        dst = e + (size_t)i * EMB + c;
    } else {                              // three 768x768 weights
        int idx = (gtid - 1536 * 256) * 4;
        if (idx < WSZ)          { src = W0 + idx;           dst = o0 + idx; }
        else if (idx < 2 * WSZ) { src = W1 + idx - WSZ;     dst = o1 + idx - WSZ; }
        else                    { src = W2 + idx - 2 * WSZ; dst = o2 + idx - 2 * WSZ; }
    }
    float4 v = *reinterpret_cast<const float4*>(src);
    pack4 p;
    p.h[0] = __float2bfloat16(v.x);
    p.h[1] = __float2bfloat16(v.y);
    p.h[2] = __float2bfloat16(v.z);
    p.h[3] = __float2bfloat16(v.w);
    *reinterpret_cast<ushort4*>(dst) = p.u;
}

// ---------------------------------------------------------------- 64x96-tile async MFMA GEMM, grid = exactly 256 blocks
// C = A1@B1^T [+ A2@B2^T] [+ bias1+bias2], row-major ld=EMB, M=2048, N=768.
// BK=64 double-buffer (40 KB LDS), global_load_lds width=16,
// 16B-chunk XOR swizzle: chunk (row,cb) at slot row*8 + (cb ^ (row&7)).
// Wave (2x2): 32 rows x 48 cols = 2x3 MFMA frags.
// Optional fused epilogue (gemm1): s1/s2 row-dots for head h = blockIdx.x, plus group-list build.
__device__ __forceinline__ void stage_ab(
    const __hip_bfloat16* __restrict__ A, int rowA0,
    const __hip_bfloat16* __restrict__ B, int rowB0, int k0,
    __hip_bfloat16* smA, __hip_bfloat16* smB, int wave, int lane)
{
#pragma unroll
    for (int i = 0; i < 2; i++) {         // A: 64 rows x 8 chunks = 512
        const int c0 = wave * 128 + i * 64;
        const int L = c0 + lane;
        const int row = L >> 3;
        const int cb = (L & 7) ^ (row & 7);
        __builtin_amdgcn_global_load_lds(
            (glb_u32*)(A + (size_t)(rowA0 + row) * EMB + k0 + cb * 8),
            (lds_u32*)(smA + c0 * 8), 16, 0, 0);
    }
#pragma unroll
    for (int i = 0; i < 3; i++) {         // B: 96 rows x 8 chunks = 768
        const int c0 = wave * 192 + i * 64;
        const int L = c0 + lane;
        const int row = L >> 3;
        const int cb = (L & 7) ^ (row & 7);
        __builtin_amdgcn_global_load_lds(
            (glb_u32*)(B + (size_t)(rowB0 + row) * EMB + k0 + cb * 8),
            (lds_u32*)(smB + c0 * 8), 16, 0, 0);
    }
}

__global__ __launch_bounds__(256) void gemm_kernel(
    const __hip_bfloat16* __restrict__ A1, const __hip_bfloat16* __restrict__ B1, int ns1,
    const __hip_bfloat16* __restrict__ A2, const __hip_bfloat16* __restrict__ B2, int ns2,
    const float* __restrict__ bias1, const float* __restrict__ bias2,
    float* __restrict__ Cf,
    const float* __restrict__ av, float* __restrict__ s1, float* __restrict__ s2,
    const int* __restrict__ h_id, int* __restrict__ cnt, int* __restrict__ lists)
{
    __shared__ __attribute__((aligned(16))) __hip_bfloat16 smA[2][4096];  // 64x64
    __shared__ __attribute__((aligned(16))) __hip_bfloat16 smB[2][6144];  // 96x64

    const int t = threadIdx.x;
    const int lane = t & 63, wave = t >> 6;
    const int wm = wave >> 1, wn = wave & 1;
    const int bm = blockIdx.y * 64, bn = blockIdx.x * 96;
    const int l15 = lane & 15, quad = lane >> 4;
    const int NS = ns1 + ns2;

    // group-list build (gemm1 only); runs after prep zeroed cnt
    if (h_id != nullptr) {
        int fid = (blockIdx.y * 8 + blockIdx.x) * 256 + t;
        if (fid < N_NODES) {
            int g = h_id[fid];
            int p = atomicAdd(&cnt[g], 1);
            lists[g * N_NODES + p] = fid;
        }
    }

    f32x4 acc[2][3];
#pragma unroll
    for (int fr = 0; fr < 2; fr++)
#pragma unroll
        for (int fc = 0; fc < 3; fc++) acc[fr][fc] = (f32x4){0.f, 0.f, 0.f, 0.f};

    stage_ab(A1, bm, B1, bn, 0, smA[0], smB[0], wave, lane);

    const int rA = wm * 32 + l15;
    const int rB = wn * 48 + l15;

    for (int s = 0; s < NS; s++) {
        __syncthreads();                  // vmcnt drain: stage s resident
        if (s + 1 < NS) {
            const int sn = s + 1;
            const __hip_bfloat16* As = (sn < ns1) ? A1 : A2;
            const __hip_bfloat16* Bs = (sn < ns1) ? B1 : B2;
            const int k0 = ((sn < ns1) ? sn : sn - ns1) * 64;
            stage_ab(As, bm, Bs, bn, k0, smA[sn & 1], smB[sn & 1], wave, lane);
        }
        const __hip_bfloat16* At = smA[s & 1];
        const __hip_bfloat16* Bt = smB[s & 1];
#pragma unroll
        for (int ks = 0; ks < 2; ks++) {
            const int cq = ks * 4 + quad;
            bf16x8 a0 = *(const bf16x8*)(At + (size_t)(rA        * 8 + (cq ^ (rA & 7)))        * 8);
            bf16x8 a1 = *(const bf16x8*)(At + (size_t)((rA + 16) * 8 + (cq ^ ((rA + 16) & 7))) * 8);
            bf16x8 b0 = *(const bf16x8*)(Bt + (size_t)(rB        * 8 + (cq ^ (rB & 7)))        * 8);
            bf16x8 b1 = *(const bf16x8*)(Bt + (size_t)((rB + 16) * 8 + (cq ^ ((rB + 16) & 7))) * 8);
            bf16x8 b2 = *(const bf16x8*)(Bt + (size_t)((rB + 32) * 8 + (cq ^ ((rB + 32) & 7))) * 8);
            acc[0][0] = __builtin_amdgcn_mfma_f32_16x16x32_bf16(a0, b0, acc[0][0], 0, 0, 0);
            acc[0][1] = __builtin_amdgcn_mfma_f32_16x16x32_bf16(a0, b1, acc[0][1], 0, 0, 0);
            acc[0][2] = __builtin_amdgcn_mfma_f32_16x16x32_bf16(a0, b2, acc[0][2], 0, 0, 0);
            acc[1][0] = __builtin_amdgcn_mfma_f32_16x16x32_bf16(a1, b0, acc[1][0], 0, 0, 0);
            acc[1][1] = __builtin_amdgcn_mfma_f32_16x16x32_bf16(a1, b1, acc[1][1], 0, 0, 0);
            acc[1][2] = __builtin_amdgcn_mfma_f32_16x16x32_bf16(a1, b2, acc[1][2], 0, 0, 0);
        }
    }

    // epilogue: C write (+bias), optional fused s1/s2
    float bv[3] = {0.f, 0.f, 0.f};
    int col[3];
#pragma unroll
    for (int fc = 0; fc < 3; fc++) {
        col[fc] = bn + wn * 48 + fc * 16 + l15;
        if (bias1 != nullptr) bv[fc] = bias1[col[fc]] + bias2[col[fc]];
    }
#pragma unroll
    for (int fr = 0; fr < 2; fr++) {
        const int r0 = bm + wm * 32 + fr * 16 + quad * 4;
#pragma unroll
        for (int r = 0; r < 4; r++)
#pragma unroll
            for (int fc = 0; fc < 3; fc++)
                Cf[(size_t)(r0 + r) * EMB + col[fc]] = acc[fr][fc][r] + bv[fc];
    }

    if (av != nullptr) {                  // s1/s2 for head h = blockIdx.x
        const int h = blockIdx.x;
        float a1v[3], a2v[3];
#pragma unroll
        for (int fc = 0; fc < 3; fc++) {
            const int cl = wn * 48 + fc * 16 + l15;   // col within head [0,96)
            a1v[fc] = av[cl];
            a2v[fc] = av[96 + cl];
        }
#pragma unroll
        for (int fr = 0; fr < 2; fr++) {
            const int r0 = bm + wm * 32 + fr * 16 + quad * 4;
#pragma unroll
            for (int r = 0; r < 4; r++) {
                float p1 = acc[fr][0][r] * a1v[0] + acc[fr][1][r] * a1v[1] + acc[fr][2][r] * a1v[2];
                float p2 = acc[fr][0][r] * a2v[0] + acc[fr][1][r] * a2v[1] + acc[fr][2][r] * a2v[2];
#pragma unroll
                for (int o = 1; o < 16; o <<= 1) {
                    p1 += __shfl_xor(p1, o);
                    p2 += __shfl_xor(p2, o);
                }
                if (l15 == 0) {
                    atomicAdd(&s1[(r0 + r) * 8 + h], p1);
                    atomicAdd(&s2[(r0 + r) * 8 + h], p2);
                }
            }
        }
    }
}

// ---------------------------------------------------------------- attention: block per (group, head, col-half)
__global__ __launch_bounds__(256) void attn_kernel(
    const float* __restrict__ Wh, const float* __restrict__ s1, const float* __restrict__ s2,
    const int* __restrict__ cnt, const int* __restrict__ lists,
    __hip_bfloat16* __restrict__ out)
{
    const int g  = blockIdx.x & 31;
    const int h  = (blockIdx.x >> 5) & 7;
    const int dh = blockIdx.x >> 8;          // 0/1 -> cols [dh*48, dh*48+48)
    const int t  = threadIdx.x;

    __shared__ int   jb[NGMAX];
    __shared__ int   qg[NGMAX];
    __shared__ float s2g[NGMAX];
    __shared__ float s1g[NGMAX][9];          // pad 9: stride-8 would 16-way conflict
    __shared__ float Whg[NGMAX][48];

    const int ng = min(cnt[g], NGMAX);
    const int* gl = lists + g * N_NODES;

    for (int j = t; j < ng; j += 256) {
        int node = gl[j];
        jb[j]  = node;
        qg[j]  = node >> 8;
        s2g[j] = s2[node * 8 + h];
        float4 v0 = *reinterpret_cast<const float4*>(s1 + node * 8);
        float4 v1 = *reinterpret_cast<const float4*>(s1 + node * 8 + 4);
        s1g[j][0] = v0.x; s1g[j][1] = v0.y; s1g[j][2] = v0.z; s1g[j][3] = v0.w;
        s1g[j][4] = v1.x; s1g[j][5] = v1.y; s1g[j][6] = v1.z; s1g[j][7] = v1.w;
    }
    __syncthreads();
    for (int idx = t; idx < ng * 12; idx += 256) {
        int jc = idx / 12, dq = idx % 12;
        float4 v = *reinterpret_cast<const float4*>(
            Wh + (size_t)jb[jc] * EMB + h * DH + dh * 48 + dq * 4);
        *reinterpret_cast<float4*>(&Whg[jc][dq * 4]) = v;
    }
    __syncthreads();

    if (t < ng) {
        float m = -1e30f;
        for (int j = 0; j < ng; j++) {
            float x = s1g[t][qg[j]] + s2g[j];
            float ev = (x >= 0.f ? x : ALPHA * x) * SCALE;
            m = fmaxf(m, ev);
        }
        float S = 0.f;
        for (int j = 0; j < ng; j++) {
            float x = s1g[t][qg[j]] + s2g[j];
            float ev = (x >= 0.f ? x : ALPHA * x) * SCALE;
            S += __expf(ev - m);
        }
        const float ri = 1.f / S;

        float acc[48];
#pragma unroll
        for (int d = 0; d < 48; d++) acc[d] = 0.f;
        for (int j = 0; j < ng; j++) {
            float x = s1g[t][qg[j]] + s2g[j];
            float ev = (x >= 0.f ? x : ALPHA * x) * SCALE;
            float p = __expf(ev - m) * ri;
#pragma unroll
            for (int d = 0; d < 48; d++) acc[d] += p * Whg[j][d];
        }
        __hip_bfloat16* po = out + (size_t)jb[t] * EMB + h * DH + dh * 48;
#pragma unroll
        for (int d = 0; d < 48; d += 4) {
            pack4 pk;
            pk.h[0] = __float2bfloat16(acc[d]);
            pk.h[1] = __float2bfloat16(acc[d + 1]);
            pk.h[2] = __float2bfloat16(acc[d + 2]);
            pk.h[3] = __float2bfloat16(acc[d + 3]);
            *reinterpret_cast<ushort4*>(po + d) = pk.u;
        }
    }
}

// ---------------------------------------------------------------- launch
extern "C" void kernel_launch(void* const* d_in, const int* in_sizes, int n_in,
                              void* d_out, int out_size, void* d_ws, size_t ws_size,
                              hipStream_t stream)
{
    const float* eh     = (const float*)d_in[0];
    const float* er     = (const float*)d_in[1];
    const float* et     = (const float*)d_in[2];
    const int*   h_id   = (const int*)d_in[3];
    const float* W_w    = (const float*)d_in[4];
    const float* a      = (const float*)d_in[5];
    const float* proj_w = (const float*)d_in[6];
    const float* proj_b = (const float*)d_in[7];
    const float* skip_w = (const float*)d_in[8];
    const float* skip_b = (const float*)d_in[9];
    float* out = (float*)d_out;   // reference output dtype is f32

    char* ws = (char*)d_ws;
    __hip_bfloat16* e_ws   = (__hip_bfloat16*)(ws);
    float*          Wh_ws  = (float*)(ws + 3145728);
    __hip_bfloat16* at_ws  = (__hip_bfloat16*)(ws + 9437184);
    __hip_bfloat16* Wb_ws  = (__hip_bfloat16*)(ws + 12582912);
    __hip_bfloat16* Pb_ws  = (__hip_bfloat16*)(ws + 13762560);
    __hip_bfloat16* Sb_ws  = (__hip_bfloat16*)(ws + 14942208);
    float*          s1_ws  = (float*)(ws + 16121856);
    float*          s2_ws  = (float*)(ws + 16187392);
    int*            cnt_ws = (int*)(ws + 16252928);
    int*            lst_ws = (int*)(ws + 16253056);

    prep_kernel<<<3296, 256, 0, stream>>>(eh, er, et, W_w, proj_w, skip_w,
                                          e_ws, Wb_ws, Pb_ws, Sb_ws, cnt_ws, s1_ws);

    // Wh = e @ W_w^T (f32) + fused s1/s2 + group lists
    gemm_kernel<<<dim3(8, 32), 256, 0, stream>>>(
        e_ws, Wb_ws, 12, nullptr, nullptr, 0, nullptr, nullptr, Wh_ws,
        a, s1_ws, s2_ws, h_id, cnt_ws, lst_ws);

    attn_kernel<<<512, 256, 0, stream>>>(Wh_ws, s1_ws, s2_ws, cnt_ws, lst_ws, at_ws);

    // out = at @ proj_w^T + e @ skip_w^T + (proj_b + skip_b)  (f32)
    gemm_kernel<<<dim3(8, 32), 256, 0, stream>>>(
        at_ws, Pb_ws, 12, e_ws, Sb_ws, 12, proj_b, skip_b, out,
        nullptr, nullptr, nullptr, nullptr, nullptr, nullptr);
}

// Round 10
// 141.551 us; speedup vs baseline: 1.0448x; 1.0448x over previous
//
#include <hip/hip_runtime.h>
#include <hip/hip_bf16.h>

#define N_NODES 2048
#define EMB 768
#define NH 8
#define DH 96
#define ALPHA 0.2f
#define SCALE 0.10206207261596575f  // 96^-0.5
#define NGMAX 192
#define WSZ (EMB * EMB)

typedef __bf16 bf16x8 __attribute__((ext_vector_type(8)));
typedef float f32x4 __attribute__((ext_vector_type(4)));
typedef __attribute__((address_space(3))) unsigned int lds_u32;
typedef __attribute__((address_space(1))) const unsigned int glb_u32;

union pack4 { ushort4 u; __hip_bfloat16 h[4]; };

// ---------------------------------------------------------------- prep: concat-cast e + cast 3 weights + zero cnt
__global__ __launch_bounds__(256) void prep_kernel(
    const float* __restrict__ eh, const float* __restrict__ er, const float* __restrict__ et,
    const float* __restrict__ W0, const float* __restrict__ W1, const float* __restrict__ W2,
    __hip_bfloat16* __restrict__ e, __hip_bfloat16* __restrict__ o0,
    __hip_bfloat16* __restrict__ o1, __hip_bfloat16* __restrict__ o2, int* __restrict__ cnt)
{
    const int b = blockIdx.x;
    const int gtid = b * 256 + threadIdx.x;
    if (gtid < 32) cnt[gtid] = 0;
    const float* src;
    __hip_bfloat16* dst;
    if (b < 1536) {                       // e = concat(eh,er,et)
        int idx = gtid * 4;
        int i = idx / EMB, c = idx % EMB;
        if (c < 256)      src = eh + i * 256 + c;
        else if (c < 512) src = er + i * 256 + (c - 256);
        else              src = et + i * 256 + (c - 512);
        dst = e + (size_t)i * EMB + c;
    } else {                              // three 768x768 weights
        int idx = (gtid - 1536 * 256) * 4;
        if (idx < WSZ)          { src = W0 + idx;           dst = o0 + idx; }
        else if (idx < 2 * WSZ) { src = W1 + idx - WSZ;     dst = o1 + idx - WSZ; }
        else                    { src = W2 + idx - 2 * WSZ; dst = o2 + idx - 2 * WSZ; }
    }
    float4 v = *reinterpret_cast<const float4*>(src);
    pack4 p;
    p.h[0] = __float2bfloat16(v.x);
    p.h[1] = __float2bfloat16(v.y);
    p.h[2] = __float2bfloat16(v.z);
    p.h[3] = __float2bfloat16(v.w);
    *reinterpret_cast<ushort4*>(dst) = p.u;
}

// ================================================================ GEMM common
// 64x48 tile, grid 512 = exactly 2 blocks/CU. BK=128 double-buffer,
// global_load_lds width=16, 16B-chunk XOR swizzle: chunk (row,cb) at row*16+(cb^(row&15)).
// Wave w owns rows [w*16, w*16+16), cols all 48 (1x3 frags).
// Slot L holds chunk(row=L>>4, cb=(L&15)^(row&15)); dest = base + L*16 (wave-uniform + lane*16).

// ---------------------------------------------------------------- gemm1: Wh = e@W^T ; out = e@skip^T + (proj_b+skip_b)
__global__ __launch_bounds__(256) void gemm1_kernel(
    const __hip_bfloat16* __restrict__ A, const __hip_bfloat16* __restrict__ BW,
    const __hip_bfloat16* __restrict__ BS,
    const float* __restrict__ pb, const float* __restrict__ sb,
    float* __restrict__ Wh, float* __restrict__ out)
{
    __shared__ __attribute__((aligned(16))) __hip_bfloat16 smA[2][8192];   // 64x128
    __shared__ __attribute__((aligned(16))) __hip_bfloat16 smW[2][6144];   // 48x128
    __shared__ __attribute__((aligned(16))) __hip_bfloat16 smS[2][6144];   // 48x128

    const int t = threadIdx.x;
    const int lane = t & 63, wave = t >> 6;
    const int l15 = lane & 15, quad = lane >> 4;
    const int bm = blockIdx.y * 64, bn = blockIdx.x * 48;

    f32x4 aW[3], aS[3];
#pragma unroll
    for (int fc = 0; fc < 3; fc++) { aW[fc] = (f32x4){0,0,0,0}; aS[fc] = (f32x4){0,0,0,0}; }

    // stage k-slab k0 into buffer bi
    auto stage = [&](int k0, int bi) {
#pragma unroll
        for (int i = 0; i < 4; i++) {                   // A: 1024 chunks
            int L = t + i * 256, row = L >> 4, cb = (L & 15) ^ (row & 15);
            __builtin_amdgcn_global_load_lds(
                (glb_u32*)(A + (size_t)(bm + row) * EMB + k0 + cb * 8),
                (lds_u32*)(&smA[bi][0] + L * 8), 16, 0, 0);
        }
#pragma unroll
        for (int i = 0; i < 3; i++) {                   // BW: 768 chunks
            int L = t + i * 256, row = L >> 4, cb = (L & 15) ^ (row & 15);
            __builtin_amdgcn_global_load_lds(
                (glb_u32*)(BW + (size_t)(bn + row) * EMB + k0 + cb * 8),
                (lds_u32*)(&smW[bi][0] + L * 8), 16, 0, 0);
        }
#pragma unroll
        for (int i = 0; i < 3; i++) {                   // BS: 768 chunks
            int L = t + i * 256, row = L >> 4, cb = (L & 15) ^ (row & 15);
            __builtin_amdgcn_global_load_lds(
                (glb_u32*)(BS + (size_t)(bn + row) * EMB + k0 + cb * 8),
                (lds_u32*)(&smS[bi][0] + L * 8), 16, 0, 0);
        }
    };

    stage(0, 0);
    const int rA = wave * 16 + l15;
    for (int s = 0; s < 6; s++) {
        __syncthreads();                  // vmcnt drain: stage s resident
        if (s < 5) stage((s + 1) * 128, (s + 1) & 1);
        const __hip_bfloat16* At = smA[s & 1];
        const __hip_bfloat16* Wt = smW[s & 1];
        const __hip_bfloat16* St = smS[s & 1];
#pragma unroll
        for (int ks = 0; ks < 4; ks++) {
            const int cq = ks * 4 + quad;
            bf16x8 a = *(const bf16x8*)(At + (size_t)((rA << 4) + (cq ^ (rA & 15))) * 8);
#pragma unroll
            for (int fc = 0; fc < 3; fc++) {
                const int rB = fc * 16 + l15;
                bf16x8 bw = *(const bf16x8*)(Wt + (size_t)((rB << 4) + (cq ^ (rB & 15))) * 8);
                bf16x8 bs = *(const bf16x8*)(St + (size_t)((rB << 4) + (cq ^ (rB & 15))) * 8);
                aW[fc] = __builtin_amdgcn_mfma_f32_16x16x32_bf16(a, bw, aW[fc], 0, 0, 0);
                aS[fc] = __builtin_amdgcn_mfma_f32_16x16x32_bf16(a, bs, aS[fc], 0, 0, 0);
            }
        }
    }

    const int r0 = bm + wave * 16 + quad * 4;
#pragma unroll
    for (int fc = 0; fc < 3; fc++) {
        const int col = bn + fc * 16 + l15;
        const float bv = pb[col] + sb[col];
#pragma unroll
        for (int r = 0; r < 4; r++) {
            Wh[(size_t)(r0 + r) * EMB + col]  = aW[fc][r];
            out[(size_t)(r0 + r) * EMB + col] = aS[fc][r] + bv;
        }
    }
}

// ---------------------------------------------------------------- gemm2: out += at @ proj^T
__global__ __launch_bounds__(256) void gemm2_kernel(
    const __hip_bfloat16* __restrict__ A, const __hip_bfloat16* __restrict__ B,
    float* __restrict__ out)
{
    __shared__ __attribute__((aligned(16))) __hip_bfloat16 smA[2][8192];   // 64x128
    __shared__ __attribute__((aligned(16))) __hip_bfloat16 smB[2][6144];   // 48x128

    const int t = threadIdx.x;
    const int lane = t & 63, wave = t >> 6;
    const int l15 = lane & 15, quad = lane >> 4;
    const int bm = blockIdx.y * 64, bn = blockIdx.x * 48;

    f32x4 acc[3];
#pragma unroll
    for (int fc = 0; fc < 3; fc++) acc[fc] = (f32x4){0, 0, 0, 0};

    auto stage = [&](int k0, int bi) {
#pragma unroll
        for (int i = 0; i < 4; i++) {
            int L = t + i * 256, row = L >> 4, cb = (L & 15) ^ (row & 15);
            __builtin_amdgcn_global_load_lds(
                (glb_u32*)(A + (size_t)(bm + row) * EMB + k0 + cb * 8),
                (lds_u32*)(&smA[bi][0] + L * 8), 16, 0, 0);
        }
#pragma unroll
        for (int i = 0; i < 3; i++) {
            int L = t + i * 256, row = L >> 4, cb = (L & 15) ^ (row & 15);
            __builtin_amdgcn_global_load_lds(
                (glb_u32*)(B + (size_t)(bn + row) * EMB + k0 + cb * 8),
                (lds_u32*)(&smB[bi][0] + L * 8), 16, 0, 0);
        }
    };

    stage(0, 0);
    const int rA = wave * 16 + l15;
    for (int s = 0; s < 6; s++) {
        __syncthreads();
        if (s < 5) stage((s + 1) * 128, (s + 1) & 1);
        const __hip_bfloat16* At = smA[s & 1];
        const __hip_bfloat16* Bt = smB[s & 1];
#pragma unroll
        for (int ks = 0; ks < 4; ks++) {
            const int cq = ks * 4 + quad;
            bf16x8 a = *(const bf16x8*)(At + (size_t)((rA << 4) + (cq ^ (rA & 15))) * 8);
#pragma unroll
            for (int fc = 0; fc < 3; fc++) {
                const int rB = fc * 16 + l15;
                bf16x8 b = *(const bf16x8*)(Bt + (size_t)((rB << 4) + (cq ^ (rB & 15))) * 8);
                acc[fc] = __builtin_amdgcn_mfma_f32_16x16x32_bf16(a, b, acc[fc], 0, 0, 0);
            }
        }
    }

    const int r0 = bm + wave * 16 + quad * 4;
#pragma unroll
    for (int fc = 0; fc < 3; fc++) {
        const int col = bn + fc * 16 + l15;
#pragma unroll
        for (int r = 0; r < 4; r++) {
            float* p = &out[(size_t)(r0 + r) * EMB + col];
            *p = *p + acc[fc][r];
        }
    }
}

// ---------------------------------------------------------------- s1/s2 + group lists (R8-proven)
__global__ __launch_bounds__(256) void s12g_kernel(
    const float* __restrict__ Wh, const float* __restrict__ a,
    float* __restrict__ s1, float* __restrict__ s2,
    const int* __restrict__ h_id, int* __restrict__ cnt, int* __restrict__ lists)
{
    int gid = blockIdx.x * 256 + threadIdx.x;  // [0, N*NH)
    if (gid < N_NODES) {
        int g = h_id[gid];
        int p = atomicAdd(&cnt[g], 1);
        lists[g * N_NODES + p] = gid;
    }
    int i = gid >> 3, h = gid & 7;
    const float* wr = Wh + (size_t)i * EMB + h * DH;
    float acc1 = 0.f, acc2 = 0.f;
    for (int d = 0; d < DH; d++) {
        float w = wr[d];
        acc1 += w * a[d];
        acc2 += w * a[DH + d];
    }
    s1[gid] = acc1;
    s2[gid] = acc2;
}

// ---------------------------------------------------------------- attention: block per (group, head, col-half) (R8-proven)
__global__ __launch_bounds__(256) void attn_kernel(
    const float* __restrict__ Wh, const float* __restrict__ s1, const float* __restrict__ s2,
    const int* __restrict__ cnt, const int* __restrict__ lists,
    __hip_bfloat16* __restrict__ out)
{
    const int g  = blockIdx.x & 31;
    const int h  = (blockIdx.x >> 5) & 7;
    const int dh = blockIdx.x >> 8;          // 0/1 -> cols [dh*48, dh*48+48)
    const int t  = threadIdx.x;

    __shared__ int   jb[NGMAX];
    __shared__ int   qg[NGMAX];
    __shared__ float s2g[NGMAX];
    __shared__ float s1g[NGMAX][9];          // pad 9: stride-8 would 16-way conflict
    __shared__ float Whg[NGMAX][48];

    const int ng = min(cnt[g], NGMAX);
    const int* gl = lists + g * N_NODES;

    for (int j = t; j < ng; j += 256) {
        int node = gl[j];
        jb[j]  = node;
        qg[j]  = node >> 8;
        s2g[j] = s2[node * 8 + h];
        float4 v0 = *reinterpret_cast<const float4*>(s1 + node * 8);
        float4 v1 = *reinterpret_cast<const float4*>(s1 + node * 8 + 4);
        s1g[j][0] = v0.x; s1g[j][1] = v0.y; s1g[j][2] = v0.z; s1g[j][3] = v0.w;
        s1g[j][4] = v1.x; s1g[j][5] = v1.y; s1g[j][6] = v1.z; s1g[j][7] = v1.w;
    }
    __syncthreads();
    for (int idx = t; idx < ng * 12; idx += 256) {
        int jc = idx / 12, dq = idx % 12;
        float4 v = *reinterpret_cast<const float4*>(
            Wh + (size_t)jb[jc] * EMB + h * DH + dh * 48 + dq * 4);
        *reinterpret_cast<float4*>(&Whg[jc][dq * 4]) = v;
    }
    __syncthreads();

    if (t < ng) {
        float m = -1e30f;
        for (int j = 0; j < ng; j++) {
            float x = s1g[t][qg[j]] + s2g[j];
            float ev = (x >= 0.f ? x : ALPHA * x) * SCALE;
            m = fmaxf(m, ev);
        }
        float S = 0.f;
        for (int j = 0; j < ng; j++) {
            float x = s1g[t][qg[j]] + s2g[j];
            float ev = (x >= 0.f ? x : ALPHA * x) * SCALE;
            S += __expf(ev - m);
        }
        const float ri = 1.f / S;

        float acc[48];
#pragma unroll
        for (int d = 0; d < 48; d++) acc[d] = 0.f;
        for (int j = 0; j < ng; j++) {
            float x = s1g[t][qg[j]] + s2g[j];
            float ev = (x >= 0.f ? x : ALPHA * x) * SCALE;
            float p = __expf(ev - m) * ri;
#pragma unroll
            for (int d = 0; d < 48; d++) acc[d] += p * Whg[j][d];
        }
        __hip_bfloat16* po = out + (size_t)jb[t] * EMB + h * DH + dh * 48;
#pragma unroll
        for (int d = 0; d < 48; d += 4) {
            pack4 pk;
            pk.h[0] = __float2bfloat16(acc[d]);
            pk.h[1] = __float2bfloat16(acc[d + 1]);
            pk.h[2] = __float2bfloat16(acc[d + 2]);
            pk.h[3] = __float2bfloat16(acc[d + 3]);
            *reinterpret_cast<ushort4*>(po + d) = pk.u;
        }
    }
}

// ---------------------------------------------------------------- launch
extern "C" void kernel_launch(void* const* d_in, const int* in_sizes, int n_in,
                              void* d_out, int out_size, void* d_ws, size_t ws_size,
                              hipStream_t stream)
{
    const float* eh     = (const float*)d_in[0];
    const float* er     = (const float*)d_in[1];
    const float* et     = (const float*)d_in[2];
    const int*   h_id   = (const int*)d_in[3];
    const float* W_w    = (const float*)d_in[4];
    const float* a      = (const float*)d_in[5];
    const float* proj_w = (const float*)d_in[6];
    const float* proj_b = (const float*)d_in[7];
    const float* skip_w = (const float*)d_in[8];
    const float* skip_b = (const float*)d_in[9];
    float* out = (float*)d_out;   // reference output dtype is f32

    char* ws = (char*)d_ws;
    __hip_bfloat16* e_ws   = (__hip_bfloat16*)(ws);
    float*          Wh_ws  = (float*)(ws + 3145728);
    __hip_bfloat16* at_ws  = (__hip_bfloat16*)(ws + 9437184);
    __hip_bfloat16* Wb_ws  = (__hip_bfloat16*)(ws + 12582912);
    __hip_bfloat16* Pb_ws  = (__hip_bfloat16*)(ws + 13762560);
    __hip_bfloat16* Sb_ws  = (__hip_bfloat16*)(ws + 14942208);
    float*          s1_ws  = (float*)(ws + 16121856);
    float*          s2_ws  = (float*)(ws + 16187392);
    int*            cnt_ws = (int*)(ws + 16252928);
    int*            lst_ws = (int*)(ws + 16253056);

    prep_kernel<<<3264, 256, 0, stream>>>(eh, er, et, W_w, proj_w, skip_w,
                                          e_ws, Wb_ws, Pb_ws, Sb_ws, cnt_ws);

    // Wh = e@W^T ; out = e@skip^T + (proj_b+skip_b)
    gemm1_kernel<<<dim3(16, 32), 256, 0, stream>>>(
        e_ws, Wb_ws, Sb_ws, proj_b, skip_b, Wh_ws, out);

    s12g_kernel<<<64, 256, 0, stream>>>(Wh_ws, a, s1_ws, s2_ws, h_id, cnt_ws, lst_ws);

    attn_kernel<<<512, 256, 0, stream>>>(Wh_ws, s1_ws, s2_ws, cnt_ws, lst_ws, at_ws);

    // out += at @ proj^T
    gemm2_kernel<<<dim3(16, 32), 256, 0, stream>>>(at_ws, Pb_ws, out);
}